// Round 7
// baseline (80.341 us; speedup 1.0000x reference)
//
#include <hip/hip_runtime.h>

// B=64, IDF=128, CDF=256, L=256, S2=1024.
// Full-fp16 pipeline, 3 kernels:
//   tcvt_all : W -> W^T fp16 + W plain fp16 ; ctx -> ctx^T fp16 + ctx plain fp16
//   G1 : M = wc(f32->fp16 on-fly) @ W^T(fp16)     [8192x256], 128x64 tiles, 256 blk
//   FUSED: logits = M @ ctx^T, softmax, out2 = P^T (coalesced via LDS),
//          Yt = P @ ctx^T' (PV), out1 = Yt @ W^T' (B-frags direct from L2)

typedef unsigned short u16;
typedef _Float16 f16;
typedef __attribute__((ext_vector_type(8))) _Float16 f16x8;    // 4 VGPRs
typedef __attribute__((ext_vector_type(4))) float f32x4;       // MFMA acc
typedef __attribute__((ext_vector_type(4))) unsigned int u32x4;

#define MFMA_F16(a, b, c) __builtin_amdgcn_mfma_f32_16x16x32_f16((a), (b), (c), 0, 0, 0)

__device__ __forceinline__ u16 f2h(float v) {
    f16 h = (f16)v;                      // v_cvt_f16_f32, RNE
    return __builtin_bit_cast(u16, h);
}
__device__ __forceinline__ float h2f(u16 h) {
    return (float)__builtin_bit_cast(f16, h);
}
__device__ __forceinline__ unsigned pk2h(float a, float b) {
    return (unsigned)f2h(a) | ((unsigned)f2h(b) << 16);
}
// XCD-chunked bijective block swizzle (grid size divisible by 8)
__device__ __forceinline__ int xcd_swz(int bid, int nwg) {
    return (bid & 7) * (nwg >> 3) + (bid >> 3);
}

// ---------------------------------------------------------------------------
// One launch: z<64 -> ctx mat z: CtP (plain fp16) + CtH (transposed fp16);
//             z>=64 -> W band: Wp (plain fp16) + WtH (transposed fp16).
// grid (8, 8, 68), block 256.
__global__ void k_tcvt_all(const float* __restrict__ Wsrc,
                           const float* __restrict__ ctx,
                           u16* __restrict__ WtH, u16* __restrict__ Wp,
                           u16* __restrict__ CtH, u16* __restrict__ CtP) {
    __shared__ float tile[32][33];
    const int z = blockIdx.z;
    const int tx = threadIdx.x & 31, ty0 = threadIdx.x >> 5;   // 32 x 8
    if (z < 64) {
        const float* s = ctx + (size_t)z * 65536;
        const int c0 = blockIdx.x * 32, r0 = blockIdx.y * 32;
#pragma unroll
        for (int i = 0; i < 4; i++) {
            int ty = ty0 + i * 8;
            float v = s[(size_t)(r0 + ty) * 256 + c0 + tx];
            tile[ty][tx] = v;
            CtP[(size_t)z * 65536 + (size_t)(r0 + ty) * 256 + c0 + tx] = f2h(v);
        }
        __syncthreads();
#pragma unroll
        for (int i = 0; i < 4; i++) {
            int ty = ty0 + i * 8;
            CtH[(size_t)z * 65536 + (size_t)(c0 + ty) * 256 + r0 + tx] = f2h(tile[tx][ty]);
        }
    } else {
        const int r0 = (z - 64) * 256 + blockIdx.y * 32;       // W rows
        const int c0 = blockIdx.x * 32;
#pragma unroll
        for (int i = 0; i < 4; i++) {
            int ty = ty0 + i * 8;
            float v = Wsrc[(size_t)(r0 + ty) * 256 + c0 + tx];
            tile[ty][tx] = v;
            Wp[(size_t)(r0 + ty) * 256 + c0 + tx] = f2h(v);
        }
        __syncthreads();
#pragma unroll
        for (int i = 0; i < 4; i++) {
            int ty = ty0 + i * 8;
            WtH[(size_t)(c0 + ty) * 1024 + r0 + tx] = f2h(tile[tx][ty]);
        }
    }
}

// ---------------------------------------------------------------------------
// fp16 MFMA GEMM: D[m][n] = sum_k A[m][k] * BT[n][k].  BK=64, 4 waves (2x2),
// wave tile (FM*16)x(FN*16). Double-buffered swizzled LDS (group ^ (row&7)).
// Banded coalesced staging. EPI: 0 = f32 out, 1 = fp16 out.
template<int BM, int BN, int FM, int FN, bool AF32, bool BF32, int EPI>
__global__ __launch_bounds__(256, 2) void k_gemm5(
    const float* __restrict__ Af, const u16* __restrict__ Ah,
    const float* __restrict__ Bf, const u16* __restrict__ Bh,
    u16* __restrict__ outH, float* __restrict__ outF,
    int NBX, int NBY, int N, int K,
    long long sA, long long sB, long long sO)
{
    static_assert(2 * FM * 16 == BM && 2 * FN * 16 == BN, "2x2 waves");
    __shared__ __align__(16) u16 As[2][BM * 64];
    __shared__ __align__(16) u16 Bs[2][BN * 64];

    const int sbl = xcd_swz((int)blockIdx.x, (int)gridDim.x);
    const int bx = sbl % NBX;
    const int by = (sbl / NBX) % NBY;
    const int bz = sbl / (NBX * NBY);
    const int m0 = by * BM, n0 = bx * BN;

    const int t = threadIdx.x;
    const int lane = t & 63, wid = t >> 6;
    const int g = lane >> 4, r = lane & 15;
    const int mB = (wid >> 1) * FM * 16, nB = (wid & 1) * FN * 16;

    constexpr int PA = AF32 ? BM / 16 : BM / 32;   // staging passes
    constexpr int PB = BF32 ? BN / 16 : BN / 32;

    const float* Afp = nullptr; const u16* Ahp = nullptr;
    const float* Bfp = nullptr; const u16* Bhp = nullptr;
    if constexpr (AF32) Afp = Af + (size_t)bz * sA; else Ahp = Ah + (size_t)bz * sA;
    if constexpr (BF32) Bfp = Bf + (size_t)bz * sB; else Bhp = Bh + (size_t)bz * sB;

    float4 fa[AF32 ? PA : 1]; u32x4 ua[AF32 ? 1 : PA];
    float4 fb[BF32 ? PB : 1]; u32x4 ub[BF32 ? 1 : PB];

    auto LOAD = [&](int k0) {
        if constexpr (AF32) {
            const int row = t >> 4, f4 = t & 15;
#pragma unroll
            for (int i = 0; i < PA; i++)
                fa[i] = *((const float4*)(Afp + (size_t)(m0 + i * 16 + row) * K + k0) + f4);
        } else {
            const int row = t >> 3, grp = t & 7;
#pragma unroll
            for (int i = 0; i < PA; i++)
                ua[i] = *((const u32x4*)(Ahp + (size_t)(m0 + i * 32 + row) * K + k0) + grp);
        }
        if constexpr (BF32) {
            const int row = t >> 4, f4 = t & 15;
#pragma unroll
            for (int i = 0; i < PB; i++)
                fb[i] = *((const float4*)(Bfp + (size_t)(n0 + i * 16 + row) * K + k0) + f4);
        } else {
            const int row = t >> 3, grp = t & 7;
#pragma unroll
            for (int i = 0; i < PB; i++)
                ub[i] = *((const u32x4*)(Bhp + (size_t)(n0 + i * 32 + row) * K + k0) + grp);
        }
    };

    auto STORE = [&](int bi) {
        if constexpr (AF32) {
            const int row0 = t >> 4, grp = (t & 15) >> 1, half = t & 1;
#pragma unroll
            for (int i = 0; i < PA; i++) {
                const int row = i * 16 + row0;
                uint2 d = make_uint2(pk2h(fa[i].x, fa[i].y), pk2h(fa[i].z, fa[i].w));
                *(uint2*)&As[bi][row * 64 + ((grp ^ (row & 7)) << 3) + (half << 2)] = d;
            }
        } else {
            const int row0 = t >> 3, grp = t & 7;
#pragma unroll
            for (int i = 0; i < PA; i++) {
                const int row = i * 32 + row0;
                *(u32x4*)&As[bi][row * 64 + ((grp ^ (row & 7)) << 3)] = ua[i];
            }
        }
        if constexpr (BF32) {
            const int row0 = t >> 4, grp = (t & 15) >> 1, half = t & 1;
#pragma unroll
            for (int i = 0; i < PB; i++) {
                const int row = i * 16 + row0;
                uint2 d = make_uint2(pk2h(fb[i].x, fb[i].y), pk2h(fb[i].z, fb[i].w));
                *(uint2*)&Bs[bi][row * 64 + ((grp ^ (row & 7)) << 3) + (half << 2)] = d;
            }
        } else {
            const int row0 = t >> 3, grp = t & 7;
#pragma unroll
            for (int i = 0; i < PB; i++) {
                const int row = i * 32 + row0;
                *(u32x4*)&Bs[bi][row * 64 + ((grp ^ (row & 7)) << 3)] = ub[i];
            }
        }
    };

    f32x4 acc[FM][FN] = {};
    int cur = 0;
    LOAD(0);
    STORE(0);
    __syncthreads();

    const int nt = K >> 6;
    for (int tt = 0; tt < nt; ++tt) {
        if (tt + 1 < nt) LOAD((tt + 1) << 6);

#pragma unroll
        for (int kh = 0; kh < 2; kh++) {
            f16x8 aF[FM], bF[FN];
#pragma unroll
            for (int mi = 0; mi < FM; mi++) {
                const int row = mB + 16 * mi + r;
                const int slot = ((kh << 2) | g) ^ (row & 7);
                aF[mi] = *(const f16x8*)&As[cur][row * 64 + slot * 8];
            }
#pragma unroll
            for (int ni = 0; ni < FN; ni++) {
                const int row = nB + 16 * ni + r;
                const int slot = ((kh << 2) | g) ^ (row & 7);
                bF[ni] = *(const f16x8*)&Bs[cur][row * 64 + slot * 8];
            }
#pragma unroll
            for (int mi = 0; mi < FM; mi++)
#pragma unroll
                for (int ni = 0; ni < FN; ni++)
                    acc[mi][ni] = MFMA_F16(aF[mi], bF[ni], acc[mi][ni]);
        }

        if (tt + 1 < nt) STORE(cur ^ 1);
        __syncthreads();
        cur ^= 1;
    }

#pragma unroll
    for (int mi = 0; mi < FM; mi++)
#pragma unroll
        for (int ni = 0; ni < FN; ni++)
#pragma unroll
            for (int rr = 0; rr < 4; rr++) {
                const int row = m0 + mB + 16 * mi + 4 * g + rr;  // C/D: row=4*(lane>>4)+reg
                const int col = n0 + nB + 16 * ni + r;           //      col=lane&15
                const float v = acc[mi][ni][rr];
                const size_t o = (size_t)bz * sO + (size_t)row * N + col;
                if constexpr (EPI == 0) outF[o] = v;
                else outH[o] = f2h(v);
            }
}

// ---------------------------------------------------------------------------
// FUSED: logits = M @ ctx (via CtH) -> softmax -> P ->
//        out2 = P^T (coalesced via LDS), Yt = P @ ctx^T' (via CtP, in LDS),
//        out1 = Yt @ W^T' (A = Yt from LDS, B-frags of Wp direct from L2).
// 512 blocks x 256 thr; block = 16 rows of one batch, 4 waves split N.
__global__ __launch_bounds__(256, 2) void k_fused2(
    const u16* __restrict__ Mh, const u16* __restrict__ CtH,
    const u16* __restrict__ CtP, const u16* __restrict__ Wp,
    float* __restrict__ out1, float* __restrict__ out2)
{
    __shared__ __align__(16) u16 smA[16 * 256];
    __shared__ __align__(16) u16 smB[256 * 64];
    __shared__ float red[16][4];

    const int sbl = xcd_swz((int)blockIdx.x, (int)gridDim.x);
    const int b  = sbl >> 3;
    const int m0 = (sbl & 7) * 16;
    const int t = threadIdx.x;
    const int lane = t & 63, w = t >> 6;
    const int g = lane >> 4, r = lane & 15;

    // stage A once (16 rows of Mh), 32 groups/row, slot = grp ^ (row&7)
    {
        const u32x4* src = (const u32x4*)(Mh + (size_t)(b * 128 + m0) * 256);
#pragma unroll
        for (int i = 0; i < 2; i++) {
            const int row = i * 8 + (t >> 5), grp = t & 31;
            u32x4 v = src[row * 32 + grp];
            *(u32x4*)&smA[row * 256 + ((grp ^ (row & 7)) << 3)] = v;
        }
    }
    const u16* Bsrc = CtH + (size_t)b * 65536;   // ctx^T [l][c]
    const u16* Psrc = CtP + (size_t)b * 65536;   // ctx   [c][l]

    u32x4 ub[8];
    auto BLOAD = [&](const u16* base, int kc) {
        const int row = t >> 3, grp = t & 7;
#pragma unroll
        for (int i = 0; i < 8; i++)
            ub[i] = *((const u32x4*)(base + (size_t)(i * 32 + row) * 256 + kc * 64) + grp);
    };
    auto BSTORE = [&]() {
        const int row0 = t >> 3, grp = t & 7;
#pragma unroll
        for (int i = 0; i < 8; i++) {
            const int row = i * 32 + row0;
            *(u32x4*)&smB[row * 64 + ((grp ^ (row & 7)) << 3)] = ub[i];
        }
    };

    // ---- logits: acc[ni][rr] = logit[4g+rr][w*64+16ni+r]
    f32x4 acc[4] = {};
    BLOAD(Bsrc, 0);
#pragma unroll
    for (int kc = 0; kc < 4; kc++) {
        BSTORE();
        __syncthreads();
        if (kc < 3) BLOAD(Bsrc, kc + 1);
#pragma unroll
        for (int kh = 0; kh < 2; kh++) {
            const int kq = kc * 2 + kh;
            const int aslot = (kq * 4 + g) ^ (r & 7);
            f16x8 aF = *(const f16x8*)&smA[r * 256 + aslot * 8];
#pragma unroll
            for (int ni = 0; ni < 4; ni++) {
                const int row = w * 64 + ni * 16 + r;
                const int bslot = ((kh << 2) | g) ^ (row & 7);
                f16x8 bF = *(const f16x8*)&smB[row * 64 + bslot * 8];
                acc[ni] = MFMA_F16(aF, bF, acc[ni]);
            }
        }
        __syncthreads();
    }

    // prefetch first PV chunk while softmax runs
    BLOAD(Psrc, 0);

    // ---- softmax over 256 cols (4 waves share each row via red[])
    float mx4[4], s4[4];
#pragma unroll
    for (int rr = 0; rr < 4; rr++) {
        float mx = fmaxf(fmaxf(acc[0][rr], acc[1][rr]), fmaxf(acc[2][rr], acc[3][rr]));
#pragma unroll
        for (int m = 1; m < 16; m <<= 1) mx = fmaxf(mx, __shfl_xor(mx, m));
        mx4[rr] = mx;
    }
    if (r == 0) {
#pragma unroll
        for (int rr = 0; rr < 4; rr++) red[4 * g + rr][w] = mx4[rr];
    }
    __syncthreads();
#pragma unroll
    for (int rr = 0; rr < 4; rr++) {
        const int lrow = 4 * g + rr;
        const float gmx = fmaxf(fmaxf(red[lrow][0], red[lrow][1]),
                                fmaxf(red[lrow][2], red[lrow][3]));
        float s = 0.f;
#pragma unroll
        for (int ni = 0; ni < 4; ni++) {
            float e = __expf(acc[ni][rr] - gmx);
            acc[ni][rr] = e;
            s += e;
        }
#pragma unroll
        for (int m = 1; m < 16; m <<= 1) s += __shfl_xor(s, m);
        s4[rr] = s;
    }
    __syncthreads();
    if (r == 0) {
#pragma unroll
        for (int rr = 0; rr < 4; rr++) red[4 * g + rr][w] = s4[rr];
    }
    __syncthreads();

    // ---- normalize, park P (fp16, swizzled) into smA (logits-A is dead)
#pragma unroll
    for (int rr = 0; rr < 4; rr++) {
        const int lrow = 4 * g + rr;
        const float inv = 1.f / (red[lrow][0] + red[lrow][1] +
                                 red[lrow][2] + red[lrow][3]);
#pragma unroll
        for (int ni = 0; ni < 4; ni++) {
            const float v = acc[ni][rr] * inv;
            const int col = w * 64 + ni * 16 + r;
            smA[lrow * 256 + (((col >> 3) ^ (lrow & 7)) << 3) + (col & 7)] = f2h(v);
        }
    }
    __syncthreads();

    // ---- out2 = P^T, coalesced: thread t owns column l = t, writes 64 B run
    {
        const int l = t;
        float vals[16];
#pragma unroll
        for (int row = 0; row < 16; row++)
            vals[row] = h2f(smA[row * 256 + (((l >> 3) ^ (row & 7)) << 3) + (l & 7)]);
        float4* dst = (float4*)(out2 + (size_t)b * 32768 + (size_t)l * 128 + m0);
#pragma unroll
        for (int q = 0; q < 4; q++)
            dst[q] = make_float4(vals[4 * q], vals[4 * q + 1],
                                 vals[4 * q + 2], vals[4 * q + 3]);
    }

    // ---- PV: Yt[i][c] = sum_l P[i][l] * ctx[c][l]  (BT rows = ctxP rows)
    f32x4 acc2[4] = {};
#pragma unroll
    for (int kc = 0; kc < 4; kc++) {
        BSTORE();
        __syncthreads();
        if (kc < 3) BLOAD(Psrc, kc + 1);
#pragma unroll
        for (int kh = 0; kh < 2; kh++) {
            const int kq = kc * 2 + kh;
            const int aslot = (kq * 4 + g) ^ (r & 7);
            f16x8 aF = *(const f16x8*)&smA[r * 256 + aslot * 8];
#pragma unroll
            for (int ni = 0; ni < 4; ni++) {
                const int row = w * 64 + ni * 16 + r;
                const int bslot = ((kh << 2) | g) ^ (row & 7);
                f16x8 bF = *(const f16x8*)&smB[row * 64 + bslot * 8];
                acc2[ni] = MFMA_F16(aF, bF, acc2[ni]);
            }
        }
        __syncthreads();
    }

    // ---- park Yt (fp16, swizzled) into smA (P is dead after PV's last read)
#pragma unroll
    for (int rr = 0; rr < 4; rr++) {
        const int lrow = 4 * g + rr;
#pragma unroll
        for (int ni = 0; ni < 4; ni++) {
            const int col = w * 64 + ni * 16 + r;
            smA[lrow * 256 + (((col >> 3) ^ (lrow & 7)) << 3) + (col & 7)] = f2h(acc2[ni][rr]);
        }
    }
    __syncthreads();

    // ---- out1 = Yt @ W^T': A = Yt (LDS, cached frags), B = Wp direct from L2.
    f16x8 aY[8];
#pragma unroll
    for (int kq = 0; kq < 8; kq++)
        aY[kq] = *(const f16x8*)&smA[r * 256 + (((kq * 4 + g) ^ (r & 7)) << 3)];

    const size_t gi0 = (size_t)(b * 128 + m0);
    f16x8 b0[8], b1[8];
    auto loadB = [&](f16x8 (&dst)[8], int n0, int ni) {
        const u16* base = Wp + (size_t)(n0 + ni * 16 + r) * 256 + g * 8;
#pragma unroll
        for (int kq = 0; kq < 8; kq++)
            dst[kq] = *(const f16x8*)(base + kq * 32);
    };
    auto doFrag = [&](f16x8 (&bsrc)[8], int n0, int ni) {
        f32x4 a3 = {};
#pragma unroll
        for (int kq = 0; kq < 8; kq++)
            a3 = MFMA_F16(aY[kq], bsrc[kq], a3);
        const int col = n0 + ni * 16 + r;
#pragma unroll
        for (int rr = 0; rr < 4; rr++)
            out1[(gi0 + 4 * g + rr) * 1024 + col] = a3[rr];
    };
#pragma unroll
    for (int q = 0; q < 4; q++) {
        const int n0 = q * 256 + w * 64;
        loadB(b0, n0, 0);
        loadB(b1, n0, 1);
        doFrag(b0, n0, 0);
        loadB(b0, n0, 2);
        doFrag(b1, n0, 1);
        loadB(b1, n0, 3);
        doFrag(b0, n0, 2);
        doFrag(b1, n0, 3);
    }
}

// ---------------------------------------------------------------------------
extern "C" void kernel_launch(void* const* d_in, const int* in_sizes, int n_in,
                              void* d_out, int out_size, void* d_ws, size_t ws_size,
                              hipStream_t stream) {
    const int B = 64, IDF = 128, CDF = 256, L = 256, S2 = 1024;
    const float* wc  = (const float*)d_in[0];   // [B, IDF, S2] = [8192][1024]
    const float* ctx = (const float*)d_in[1];   // [B, CDF, L]
    const float* W   = (const float*)d_in[2];   // [S2, CDF]
    float* out1 = (float*)d_out;                          // [B,IDF,S2]
    float* out2 = (float*)d_out + (size_t)B * IDF * S2;   // [B,L,IDF]

    char* ws = (char*)d_ws;
    size_t off = 0;
    auto alloc = [&](size_t bytes) -> char* {
        char* p = ws + off;
        off += (bytes + 255) & ~(size_t)255;
        return p;
    };
    u16* WtH = (u16*)alloc((size_t)CDF * S2 * 2);        // W^T fp16 [256][1024]
    u16* Wp  = (u16*)alloc((size_t)S2 * CDF * 2);        // W   fp16 [1024][256]
    u16* CtH = (u16*)alloc((size_t)B * L * CDF * 2);     // ctx^T fp16 [B][l][c]
    u16* CtP = (u16*)alloc((size_t)B * CDF * L * 2);     // ctx fp16  [B][c][l]
    u16* MH  = (u16*)alloc((size_t)B * IDF * CDF * 2);   // M fp16 [8192][256]
    (void)ws_size; // ~22 MB

    // converts (one launch): ctx -> CtH + CtP ; W -> WtH + Wp
    k_tcvt_all<<<dim3(8, 8, 68), 256, 0, stream>>>(W, ctx, WtH, Wp, CtH, CtP);

    // G1: M = wc @ W  (A = wc f32 on-fly, BT = W^T fp16), 128x64, 256 blocks
    k_gemm5<128, 64, 4, 2, true, false, 1><<<256, 256, 0, stream>>>(
        wc, nullptr, nullptr, WtH, MH, nullptr,
        4, 64, 256, 1024, 0, 0, 0);

    // FUSED: logits + softmax + out2 + PV + out1, 512 blocks
    k_fused2<<<512, 256, 0, stream>>>(MH, CtH, CtP, Wp, out1, out2);
}

// Round 8
// 58.842 us; speedup vs baseline: 1.3654x; 1.3654x over previous
//
#include <hip/hip_runtime.h>

// B=64, IDF=128, CDF=256, L=256, S2=1024.
// Full-fp16 pipeline, 3 kernels:
//   tcvt_all : W -> W^T fp16 + W plain fp16 ; ctx -> ctx^T fp16 + ctx plain fp16
//   G1 : M = wc(f32->fp16 on-fly) @ W^T(fp16)     [8192x256], 64x64 tiles, 512 blk
//   FUSED: logits = M @ ctx^T, softmax, out2 = P^T (coalesced via LDS),
//          Yt = P @ ctx^T' (PV), out1 = Yt @ W^T' (B LDS-STAGED from Wp chunks)

typedef unsigned short u16;
typedef _Float16 f16;
typedef __attribute__((ext_vector_type(8))) _Float16 f16x8;    // 4 VGPRs
typedef __attribute__((ext_vector_type(4))) float f32x4;       // MFMA acc
typedef __attribute__((ext_vector_type(4))) unsigned int u32x4;

#define MFMA_F16(a, b, c) __builtin_amdgcn_mfma_f32_16x16x32_f16((a), (b), (c), 0, 0, 0)

__device__ __forceinline__ u16 f2h(float v) {
    f16 h = (f16)v;                      // v_cvt_f16_f32, RNE
    return __builtin_bit_cast(u16, h);
}
__device__ __forceinline__ float h2f(u16 h) {
    return (float)__builtin_bit_cast(f16, h);
}
__device__ __forceinline__ unsigned pk2h(float a, float b) {
    return (unsigned)f2h(a) | ((unsigned)f2h(b) << 16);
}
// XCD-chunked bijective block swizzle (grid size divisible by 8)
__device__ __forceinline__ int xcd_swz(int bid, int nwg) {
    return (bid & 7) * (nwg >> 3) + (bid >> 3);
}

// ---------------------------------------------------------------------------
// One launch: z<64 -> ctx mat z: CtP (plain fp16) + CtH (transposed fp16);
//             z>=64 -> W band: Wp (plain fp16) + WtH (transposed fp16).
// grid (8, 8, 68), block 256.
__global__ void k_tcvt_all(const float* __restrict__ Wsrc,
                           const float* __restrict__ ctx,
                           u16* __restrict__ WtH, u16* __restrict__ Wp,
                           u16* __restrict__ CtH, u16* __restrict__ CtP) {
    __shared__ float tile[32][33];
    const int z = blockIdx.z;
    const int tx = threadIdx.x & 31, ty0 = threadIdx.x >> 5;   // 32 x 8
    if (z < 64) {
        const float* s = ctx + (size_t)z * 65536;
        const int c0 = blockIdx.x * 32, r0 = blockIdx.y * 32;
#pragma unroll
        for (int i = 0; i < 4; i++) {
            int ty = ty0 + i * 8;
            float v = s[(size_t)(r0 + ty) * 256 + c0 + tx];
            tile[ty][tx] = v;
            CtP[(size_t)z * 65536 + (size_t)(r0 + ty) * 256 + c0 + tx] = f2h(v);
        }
        __syncthreads();
#pragma unroll
        for (int i = 0; i < 4; i++) {
            int ty = ty0 + i * 8;
            CtH[(size_t)z * 65536 + (size_t)(c0 + ty) * 256 + r0 + tx] = f2h(tile[tx][ty]);
        }
    } else {
        const int r0 = (z - 64) * 256 + blockIdx.y * 32;       // W rows
        const int c0 = blockIdx.x * 32;
#pragma unroll
        for (int i = 0; i < 4; i++) {
            int ty = ty0 + i * 8;
            float v = Wsrc[(size_t)(r0 + ty) * 256 + c0 + tx];
            tile[ty][tx] = v;
            Wp[(size_t)(r0 + ty) * 256 + c0 + tx] = f2h(v);
        }
        __syncthreads();
#pragma unroll
        for (int i = 0; i < 4; i++) {
            int ty = ty0 + i * 8;
            WtH[(size_t)(c0 + ty) * 1024 + r0 + tx] = f2h(tile[tx][ty]);
        }
    }
}

// ---------------------------------------------------------------------------
// fp16 MFMA GEMM: D[m][n] = sum_k A[m][k] * BT[n][k].  BK=64, 4 waves (2x2),
// wave tile (FM*16)x(FN*16). Double-buffered swizzled LDS (group ^ (row&7)).
// Banded coalesced staging. EPI: 0 = f32 out, 1 = fp16 out.
template<int BM, int BN, int FM, int FN, bool AF32, bool BF32, int EPI>
__global__ __launch_bounds__(256, 2) void k_gemm5(
    const float* __restrict__ Af, const u16* __restrict__ Ah,
    const float* __restrict__ Bf, const u16* __restrict__ Bh,
    u16* __restrict__ outH, float* __restrict__ outF,
    int NBX, int NBY, int N, int K,
    long long sA, long long sB, long long sO)
{
    static_assert(2 * FM * 16 == BM && 2 * FN * 16 == BN, "2x2 waves");
    __shared__ __align__(16) u16 As[2][BM * 64];
    __shared__ __align__(16) u16 Bs[2][BN * 64];

    const int sbl = xcd_swz((int)blockIdx.x, (int)gridDim.x);
    const int bx = sbl % NBX;
    const int by = (sbl / NBX) % NBY;
    const int bz = sbl / (NBX * NBY);
    const int m0 = by * BM, n0 = bx * BN;

    const int t = threadIdx.x;
    const int lane = t & 63, wid = t >> 6;
    const int g = lane >> 4, r = lane & 15;
    const int mB = (wid >> 1) * FM * 16, nB = (wid & 1) * FN * 16;

    constexpr int PA = AF32 ? BM / 16 : BM / 32;   // staging passes
    constexpr int PB = BF32 ? BN / 16 : BN / 32;

    const float* Afp = nullptr; const u16* Ahp = nullptr;
    const float* Bfp = nullptr; const u16* Bhp = nullptr;
    if constexpr (AF32) Afp = Af + (size_t)bz * sA; else Ahp = Ah + (size_t)bz * sA;
    if constexpr (BF32) Bfp = Bf + (size_t)bz * sB; else Bhp = Bh + (size_t)bz * sB;

    float4 fa[AF32 ? PA : 1]; u32x4 ua[AF32 ? 1 : PA];
    float4 fb[BF32 ? PB : 1]; u32x4 ub[BF32 ? 1 : PB];

    auto LOAD = [&](int k0) {
        if constexpr (AF32) {
            const int row = t >> 4, f4 = t & 15;
#pragma unroll
            for (int i = 0; i < PA; i++)
                fa[i] = *((const float4*)(Afp + (size_t)(m0 + i * 16 + row) * K + k0) + f4);
        } else {
            const int row = t >> 3, grp = t & 7;
#pragma unroll
            for (int i = 0; i < PA; i++)
                ua[i] = *((const u32x4*)(Ahp + (size_t)(m0 + i * 32 + row) * K + k0) + grp);
        }
        if constexpr (BF32) {
            const int row = t >> 4, f4 = t & 15;
#pragma unroll
            for (int i = 0; i < PB; i++)
                fb[i] = *((const float4*)(Bfp + (size_t)(n0 + i * 16 + row) * K + k0) + f4);
        } else {
            const int row = t >> 3, grp = t & 7;
#pragma unroll
            for (int i = 0; i < PB; i++)
                ub[i] = *((const u32x4*)(Bhp + (size_t)(n0 + i * 32 + row) * K + k0) + grp);
        }
    };

    auto STORE = [&](int bi) {
        if constexpr (AF32) {
            const int row0 = t >> 4, grp = (t & 15) >> 1, half = t & 1;
#pragma unroll
            for (int i = 0; i < PA; i++) {
                const int row = i * 16 + row0;
                uint2 d = make_uint2(pk2h(fa[i].x, fa[i].y), pk2h(fa[i].z, fa[i].w));
                *(uint2*)&As[bi][row * 64 + ((grp ^ (row & 7)) << 3) + (half << 2)] = d;
            }
        } else {
            const int row0 = t >> 3, grp = t & 7;
#pragma unroll
            for (int i = 0; i < PA; i++) {
                const int row = i * 32 + row0;
                *(u32x4*)&As[bi][row * 64 + ((grp ^ (row & 7)) << 3)] = ua[i];
            }
        }
        if constexpr (BF32) {
            const int row0 = t >> 4, grp = (t & 15) >> 1, half = t & 1;
#pragma unroll
            for (int i = 0; i < PB; i++) {
                const int row = i * 16 + row0;
                uint2 d = make_uint2(pk2h(fb[i].x, fb[i].y), pk2h(fb[i].z, fb[i].w));
                *(uint2*)&Bs[bi][row * 64 + ((grp ^ (row & 7)) << 3) + (half << 2)] = d;
            }
        } else {
            const int row0 = t >> 3, grp = t & 7;
#pragma unroll
            for (int i = 0; i < PB; i++) {
                const int row = i * 32 + row0;
                *(u32x4*)&Bs[bi][row * 64 + ((grp ^ (row & 7)) << 3)] = ub[i];
            }
        }
    };

    f32x4 acc[FM][FN] = {};
    int cur = 0;
    LOAD(0);
    STORE(0);
    __syncthreads();

    const int nt = K >> 6;
    for (int tt = 0; tt < nt; ++tt) {
        if (tt + 1 < nt) LOAD((tt + 1) << 6);

#pragma unroll
        for (int kh = 0; kh < 2; kh++) {
            f16x8 aF[FM], bF[FN];
#pragma unroll
            for (int mi = 0; mi < FM; mi++) {
                const int row = mB + 16 * mi + r;
                const int slot = ((kh << 2) | g) ^ (row & 7);
                aF[mi] = *(const f16x8*)&As[cur][row * 64 + slot * 8];
            }
#pragma unroll
            for (int ni = 0; ni < FN; ni++) {
                const int row = nB + 16 * ni + r;
                const int slot = ((kh << 2) | g) ^ (row & 7);
                bF[ni] = *(const f16x8*)&Bs[cur][row * 64 + slot * 8];
            }
#pragma unroll
            for (int mi = 0; mi < FM; mi++)
#pragma unroll
                for (int ni = 0; ni < FN; ni++)
                    acc[mi][ni] = MFMA_F16(aF[mi], bF[ni], acc[mi][ni]);
        }

        if (tt + 1 < nt) STORE(cur ^ 1);
        __syncthreads();
        cur ^= 1;
    }

#pragma unroll
    for (int mi = 0; mi < FM; mi++)
#pragma unroll
        for (int ni = 0; ni < FN; ni++)
#pragma unroll
            for (int rr = 0; rr < 4; rr++) {
                const int row = m0 + mB + 16 * mi + 4 * g + rr;  // C/D: row=4*(lane>>4)+reg
                const int col = n0 + nB + 16 * ni + r;           //      col=lane&15
                const float v = acc[mi][ni][rr];
                const size_t o = (size_t)bz * sO + (size_t)row * N + col;
                if constexpr (EPI == 0) outF[o] = v;
                else outH[o] = f2h(v);
            }
}

// ---------------------------------------------------------------------------
// FUSED: logits = M @ ctx (via CtH) -> softmax -> P ->
//        out2 = P^T (coalesced via LDS), Yt = P @ ctx^T' (via CtP, parked LDS),
//        out1 = Yt @ W^T' (A = Yt regs, B = Wp chunks LDS-STAGED, coalesced).
// 512 blocks x 256 thr; block = 16 rows of one batch, 4 waves split N.
__global__ __launch_bounds__(256, 2) void k_fused3(
    const u16* __restrict__ Mh, const u16* __restrict__ CtH,
    const u16* __restrict__ CtP, const u16* __restrict__ Wp,
    float* __restrict__ out1, float* __restrict__ out2)
{
    __shared__ __align__(16) u16 smA[16 * 256];
    __shared__ __align__(16) u16 smB[256 * 64];
    __shared__ float red[16][4];

    const int sbl = xcd_swz((int)blockIdx.x, (int)gridDim.x);
    const int b  = sbl >> 3;
    const int m0 = (sbl & 7) * 16;
    const int t = threadIdx.x;
    const int lane = t & 63, w = t >> 6;
    const int g = lane >> 4, r = lane & 15;

    // stage A once (16 rows of Mh), 32 groups/row, slot = grp ^ (row&7)
    {
        const u32x4* src = (const u32x4*)(Mh + (size_t)(b * 128 + m0) * 256);
#pragma unroll
        for (int i = 0; i < 2; i++) {
            const int row = i * 8 + (t >> 5), grp = t & 31;
            u32x4 v = src[row * 32 + grp];
            *(u32x4*)&smA[row * 256 + ((grp ^ (row & 7)) << 3)] = v;
        }
    }
    const u16* Bsrc = CtH + (size_t)b * 65536;   // ctx^T [l][c]
    const u16* Psrc = CtP + (size_t)b * 65536;   // ctx   [c][l]

    u32x4 ub[8];
    auto BLOAD = [&](const u16* base, int kc) {
        const int row = t >> 3, grp = t & 7;
#pragma unroll
        for (int i = 0; i < 8; i++)
            ub[i] = *((const u32x4*)(base + (size_t)(i * 32 + row) * 256 + kc * 64) + grp);
    };
    auto BSTORE = [&]() {
        const int row0 = t >> 3, grp = t & 7;
#pragma unroll
        for (int i = 0; i < 8; i++) {
            const int row = i * 32 + row0;
            *(u32x4*)&smB[row * 64 + ((grp ^ (row & 7)) << 3)] = ub[i];
        }
    };

    // ---- logits: acc[ni][rr] = logit[4g+rr][w*64+16ni+r]
    f32x4 acc[4] = {};
    BLOAD(Bsrc, 0);
#pragma unroll
    for (int kc = 0; kc < 4; kc++) {
        BSTORE();
        __syncthreads();
        if (kc < 3) BLOAD(Bsrc, kc + 1);
#pragma unroll
        for (int kh = 0; kh < 2; kh++) {
            const int kq = kc * 2 + kh;
            const int aslot = (kq * 4 + g) ^ (r & 7);
            f16x8 aF = *(const f16x8*)&smA[r * 256 + aslot * 8];
#pragma unroll
            for (int ni = 0; ni < 4; ni++) {
                const int row = w * 64 + ni * 16 + r;
                const int bslot = ((kh << 2) | g) ^ (row & 7);
                f16x8 bF = *(const f16x8*)&smB[row * 64 + bslot * 8];
                acc[ni] = MFMA_F16(aF, bF, acc[ni]);
            }
        }
        __syncthreads();
    }

    // prefetch first PV chunk while softmax runs
    BLOAD(Psrc, 0);

    // ---- softmax over 256 cols (4 waves share each row via red[])
    float mx4[4], s4[4];
#pragma unroll
    for (int rr = 0; rr < 4; rr++) {
        float mx = fmaxf(fmaxf(acc[0][rr], acc[1][rr]), fmaxf(acc[2][rr], acc[3][rr]));
#pragma unroll
        for (int m = 1; m < 16; m <<= 1) mx = fmaxf(mx, __shfl_xor(mx, m));
        mx4[rr] = mx;
    }
    if (r == 0) {
#pragma unroll
        for (int rr = 0; rr < 4; rr++) red[4 * g + rr][w] = mx4[rr];
    }
    __syncthreads();
#pragma unroll
    for (int rr = 0; rr < 4; rr++) {
        const int lrow = 4 * g + rr;
        const float gmx = fmaxf(fmaxf(red[lrow][0], red[lrow][1]),
                                fmaxf(red[lrow][2], red[lrow][3]));
        float s = 0.f;
#pragma unroll
        for (int ni = 0; ni < 4; ni++) {
            float e = __expf(acc[ni][rr] - gmx);
            acc[ni][rr] = e;
            s += e;
        }
#pragma unroll
        for (int m = 1; m < 16; m <<= 1) s += __shfl_xor(s, m);
        s4[rr] = s;
    }
    __syncthreads();
    if (r == 0) {
#pragma unroll
        for (int rr = 0; rr < 4; rr++) red[4 * g + rr][w] = s4[rr];
    }
    __syncthreads();

    // ---- normalize, park P (fp16, swizzled) into smA (logits-A is dead)
#pragma unroll
    for (int rr = 0; rr < 4; rr++) {
        const int lrow = 4 * g + rr;
        const float inv = 1.f / (red[lrow][0] + red[lrow][1] +
                                 red[lrow][2] + red[lrow][3]);
#pragma unroll
        for (int ni = 0; ni < 4; ni++) {
            const float v = acc[ni][rr] * inv;
            const int col = w * 64 + ni * 16 + r;
            smA[lrow * 256 + (((col >> 3) ^ (lrow & 7)) << 3) + (col & 7)] = f2h(v);
        }
    }
    __syncthreads();

    // ---- out2 = P^T, coalesced: thread t owns column l = t, writes 64 B run
    {
        const int l = t;
        float vals[16];
#pragma unroll
        for (int row = 0; row < 16; row++)
            vals[row] = h2f(smA[row * 256 + (((l >> 3) ^ (row & 7)) << 3) + (l & 7)]);
        float4* dst = (float4*)(out2 + (size_t)b * 32768 + (size_t)l * 128 + m0);
#pragma unroll
        for (int q = 0; q < 4; q++)
            dst[q] = make_float4(vals[4 * q], vals[4 * q + 1],
                                 vals[4 * q + 2], vals[4 * q + 3]);
    }

    // ---- PV: Yt[i][c] = sum_l P[i][l] * ctx[c][l]  (BT rows = ctxP rows)
    f32x4 acc2[4] = {};
#pragma unroll
    for (int kc = 0; kc < 4; kc++) {
        BSTORE();
        __syncthreads();
        if (kc < 3) BLOAD(Psrc, kc + 1);
        else        BLOAD(Wp, 0);           // prefetch first out1 B-chunk
#pragma unroll
        for (int kh = 0; kh < 2; kh++) {
            const int kq = kc * 2 + kh;
            const int aslot = (kq * 4 + g) ^ (r & 7);
            f16x8 aF = *(const f16x8*)&smA[r * 256 + aslot * 8];
#pragma unroll
            for (int ni = 0; ni < 4; ni++) {
                const int row = w * 64 + ni * 16 + r;
                const int bslot = ((kh << 2) | g) ^ (row & 7);
                f16x8 bF = *(const f16x8*)&smB[row * 64 + bslot * 8];
                acc2[ni] = MFMA_F16(aF, bF, acc2[ni]);
            }
        }
        __syncthreads();
    }

    // ---- park Yt (fp16, swizzled) into smA (P is dead after PV's last read)
#pragma unroll
    for (int rr = 0; rr < 4; rr++) {
        const int lrow = 4 * g + rr;
#pragma unroll
        for (int ni = 0; ni < 4; ni++) {
            const int col = w * 64 + ni * 16 + r;
            smA[lrow * 256 + (((col >> 3) ^ (lrow & 7)) << 3) + (col & 7)] = f2h(acc2[ni][rr]);
        }
    }
    __syncthreads();

    // ---- out1 = Yt @ W^T': A = Yt (regs, from LDS once), B = Wp LDS-staged.
    // N=1024 -> 4 n-super-chunks of 256; K=256 -> 4 k-chunks of 64 per super.
    f16x8 aY[8];
#pragma unroll
    for (int kq = 0; kq < 8; kq++)
        aY[kq] = *(const f16x8*)&smA[r * 256 + (((kq * 4 + g) ^ (r & 7)) << 3)];

    const size_t gi0 = (size_t)(b * 128 + m0);
#pragma unroll
    for (int ns = 0; ns < 4; ns++) {
        f32x4 acc3[4] = {};
#pragma unroll
        for (int kc = 0; kc < 4; kc++) {
            BSTORE();
            __syncthreads();
            if (kc < 3)      BLOAD(Wp + (size_t)ns * 65536, kc + 1);
            else if (ns < 3) BLOAD(Wp + (size_t)(ns + 1) * 65536, 0);
#pragma unroll
            for (int kh = 0; kh < 2; kh++) {
                f16x8 aF = aY[kc * 2 + kh];
#pragma unroll
                for (int ni = 0; ni < 4; ni++) {
                    const int row = w * 64 + ni * 16 + r;
                    const int bslot = ((kh << 2) | g) ^ (row & 7);
                    f16x8 bF = *(const f16x8*)&smB[row * 64 + bslot * 8];
                    acc3[ni] = MFMA_F16(aF, bF, acc3[ni]);
                }
            }
            __syncthreads();
        }
        // write this n-super-chunk of out1 (f32)
#pragma unroll
        for (int ni = 0; ni < 4; ni++) {
            const int col = ns * 256 + w * 64 + ni * 16 + r;
#pragma unroll
            for (int rr = 0; rr < 4; rr++)
                out1[(gi0 + 4 * g + rr) * 1024 + col] = acc3[ni][rr];
        }
    }
}

// ---------------------------------------------------------------------------
extern "C" void kernel_launch(void* const* d_in, const int* in_sizes, int n_in,
                              void* d_out, int out_size, void* d_ws, size_t ws_size,
                              hipStream_t stream) {
    const int B = 64, IDF = 128, CDF = 256, L = 256, S2 = 1024;
    const float* wc  = (const float*)d_in[0];   // [B, IDF, S2] = [8192][1024]
    const float* ctx = (const float*)d_in[1];   // [B, CDF, L]
    const float* W   = (const float*)d_in[2];   // [S2, CDF]
    float* out1 = (float*)d_out;                          // [B,IDF,S2]
    float* out2 = (float*)d_out + (size_t)B * IDF * S2;   // [B,L,IDF]

    char* ws = (char*)d_ws;
    size_t off = 0;
    auto alloc = [&](size_t bytes) -> char* {
        char* p = ws + off;
        off += (bytes + 255) & ~(size_t)255;
        return p;
    };
    u16* WtH = (u16*)alloc((size_t)CDF * S2 * 2);        // W^T fp16 [256][1024]
    u16* Wp  = (u16*)alloc((size_t)S2 * CDF * 2);        // W   fp16 [1024][256]
    u16* CtH = (u16*)alloc((size_t)B * L * CDF * 2);     // ctx^T fp16 [B][l][c]
    u16* CtP = (u16*)alloc((size_t)B * CDF * L * 2);     // ctx fp16  [B][c][l]
    u16* MH  = (u16*)alloc((size_t)B * IDF * CDF * 2);   // M fp16 [8192][256]
    (void)ws_size; // ~22 MB

    // converts (one launch): ctx -> CtH + CtP ; W -> WtH + Wp
    k_tcvt_all<<<dim3(8, 8, 68), 256, 0, stream>>>(W, ctx, WtH, Wp, CtH, CtP);

    // G1: M = wc @ W  (A = wc f32 on-fly, BT = W^T fp16), 64x64, 512 blocks
    k_gemm5<64, 64, 2, 2, true, false, 1><<<512, 256, 0, stream>>>(
        wc, nullptr, nullptr, WtH, MH, nullptr,
        4, 128, 256, 1024, 0, 0, 0);

    // FUSED: logits + softmax + out2 + PV + out1 (staged), 512 blocks
    k_fused3<<<512, 256, 0, stream>>>(MH, CtH, CtP, Wp, out1, out2);
}

// Round 9
// 55.009 us; speedup vs baseline: 1.4605x; 1.0697x over previous
//
#include <hip/hip_runtime.h>

// B=64, IDF=128, CDF=256, L=256, S2=1024.
// Full-fp16 pipeline, 3 kernels:
//   tcvt_all : W -> W^T + W plain fp16 ; ctx -> ctx^T + ctx plain fp16
//   G1 (k_gemm9): M = wc(f32->fp16) @ W^T fp16, 64x64 tiles, 512 thr, 512 blk
//   FUSED (k_fused4): 512 thr, 8 waves, 2-deep smB pipeline over 24 chunks:
//     logits = M @ ctx^T (CtH 0-3) -> softmax -> P -> out2 = P^T,
//     Yt = P @ ctx^T' (CtP 4-7), out1 = Yt @ W^T' (Wp 8-23)

typedef unsigned short u16;
typedef _Float16 f16;
typedef __attribute__((ext_vector_type(8))) _Float16 f16x8;    // 4 VGPRs
typedef __attribute__((ext_vector_type(4))) float f32x4;       // MFMA acc
typedef __attribute__((ext_vector_type(4))) unsigned int u32x4;

#define MFMA_F16(a, b, c) __builtin_amdgcn_mfma_f32_16x16x32_f16((a), (b), (c), 0, 0, 0)

__device__ __forceinline__ u16 f2h(float v) {
    f16 h = (f16)v;                      // v_cvt_f16_f32, RNE
    return __builtin_bit_cast(u16, h);
}
__device__ __forceinline__ float h2f(u16 h) {
    return (float)__builtin_bit_cast(f16, h);
}
__device__ __forceinline__ unsigned pk2h(float a, float b) {
    return (unsigned)f2h(a) | ((unsigned)f2h(b) << 16);
}
// XCD-chunked bijective block swizzle (grid size divisible by 8)
__device__ __forceinline__ int xcd_swz(int bid, int nwg) {
    return (bid & 7) * (nwg >> 3) + (bid >> 3);
}

// ---------------------------------------------------------------------------
// One launch: z<64 -> ctx mat z: CtP (plain fp16) + CtH (transposed fp16);
//             z>=64 -> W band: Wp (plain fp16) + WtH (transposed fp16).
__global__ void k_tcvt_all(const float* __restrict__ Wsrc,
                           const float* __restrict__ ctx,
                           u16* __restrict__ WtH, u16* __restrict__ Wp,
                           u16* __restrict__ CtH, u16* __restrict__ CtP) {
    __shared__ float tile[32][33];
    const int z = blockIdx.z;
    const int tx = threadIdx.x & 31, ty0 = threadIdx.x >> 5;   // 32 x 8
    if (z < 64) {
        const float* s = ctx + (size_t)z * 65536;
        const int c0 = blockIdx.x * 32, r0 = blockIdx.y * 32;
#pragma unroll
        for (int i = 0; i < 4; i++) {
            int ty = ty0 + i * 8;
            float v = s[(size_t)(r0 + ty) * 256 + c0 + tx];
            tile[ty][tx] = v;
            CtP[(size_t)z * 65536 + (size_t)(r0 + ty) * 256 + c0 + tx] = f2h(v);
        }
        __syncthreads();
#pragma unroll
        for (int i = 0; i < 4; i++) {
            int ty = ty0 + i * 8;
            CtH[(size_t)z * 65536 + (size_t)(c0 + ty) * 256 + r0 + tx] = f2h(tile[tx][ty]);
        }
    } else {
        const int r0 = (z - 64) * 256 + blockIdx.y * 32;       // W rows
        const int c0 = blockIdx.x * 32;
#pragma unroll
        for (int i = 0; i < 4; i++) {
            int ty = ty0 + i * 8;
            float v = Wsrc[(size_t)(r0 + ty) * 256 + c0 + tx];
            tile[ty][tx] = v;
            Wp[(size_t)(r0 + ty) * 256 + c0 + tx] = f2h(v);
        }
        __syncthreads();
#pragma unroll
        for (int i = 0; i < 4; i++) {
            int ty = ty0 + i * 8;
            WtH[(size_t)(c0 + ty) * 1024 + r0 + tx] = f2h(tile[tx][ty]);
        }
    }
}

// ---------------------------------------------------------------------------
// G1: M = wc @ WtH^T. 512 threads (8 waves 2m x 4n, wave tile 32x16),
// 64x64 tile, BK=64, dbuf swizzled LDS. A = f32 converted on the fly.
__global__ __launch_bounds__(512, 4) void k_gemm9(
    const float* __restrict__ Af, const u16* __restrict__ Bh,
    u16* __restrict__ outH)
{
    __shared__ __align__(16) u16 As[2][64 * 64];
    __shared__ __align__(16) u16 Bs[2][64 * 64];

    const int sbl = xcd_swz((int)blockIdx.x, (int)gridDim.x);
    const int bx = sbl & 3;            // 4 n-tiles
    const int by = sbl >> 2;           // 128 m-tiles
    const int m0 = by * 64, n0 = bx * 64;

    const int t = threadIdx.x;
    const int lane = t & 63, wid = t >> 6;
    const int g = lane >> 4, r = lane & 15;
    const int mB = (wid >> 2) * 32, nB = (wid & 3) * 16;

    // A staging: 2 passes, row = i*32 + (t>>4), float4 at (t&15)
    // B staging: 1 pass,  row = t>>3, group t&7
    float4 fa[2];
    u32x4 ub;

    auto LOAD = [&](int k0) {
#pragma unroll
        for (int i = 0; i < 2; i++)
            fa[i] = *((const float4*)(Af + (size_t)(m0 + i * 32 + (t >> 4)) * 1024 + k0) + (t & 15));
        ub = *((const u32x4*)(Bh + (size_t)(n0 + (t >> 3)) * 1024 + k0) + (t & 7));
    };
    auto STORE = [&](int bi) {
        const int grpA = (t & 15) >> 1, half = t & 1;
#pragma unroll
        for (int i = 0; i < 2; i++) {
            const int row = i * 32 + (t >> 4);
            uint2 d = make_uint2(pk2h(fa[i].x, fa[i].y), pk2h(fa[i].z, fa[i].w));
            *(uint2*)&As[bi][row * 64 + ((grpA ^ (row & 7)) << 3) + (half << 2)] = d;
        }
        const int rowB = t >> 3, grpB = t & 7;
        *(u32x4*)&Bs[bi][rowB * 64 + ((grpB ^ (rowB & 7)) << 3)] = ub;
    };

    f32x4 acc[2] = {};
    int cur = 0;
    LOAD(0);
    STORE(0);
    __syncthreads();

#pragma unroll 1
    for (int tt = 0; tt < 16; ++tt) {
        if (tt + 1 < 16) LOAD((tt + 1) << 6);
#pragma unroll
        for (int kh = 0; kh < 2; kh++) {
            f16x8 aF[2], bF;
#pragma unroll
            for (int mi = 0; mi < 2; mi++) {
                const int row = mB + 16 * mi + r;
                aF[mi] = *(const f16x8*)&As[cur][row * 64 + ((((kh << 2) | g) ^ (row & 7)) << 3)];
            }
            {
                const int row = nB + r;
                bF = *(const f16x8*)&Bs[cur][row * 64 + ((((kh << 2) | g) ^ (row & 7)) << 3)];
            }
#pragma unroll
            for (int mi = 0; mi < 2; mi++)
                acc[mi] = MFMA_F16(aF[mi], bF, acc[mi]);
        }
        if (tt + 1 < 16) STORE(cur ^ 1);
        __syncthreads();
        cur ^= 1;
    }

#pragma unroll
    for (int mi = 0; mi < 2; mi++)
#pragma unroll
        for (int rr = 0; rr < 4; rr++) {
            const int row = m0 + mB + 16 * mi + 4 * g + rr;  // C/D: row=4*(lane>>4)+reg
            const int col = n0 + nB + r;                     //      col=lane&15
            outH[(size_t)row * 256 + col] = f2h(acc[mi][rr]);
        }
}

// ---------------------------------------------------------------------------
// FUSED, 512 thr / 8 waves. Unified 24-chunk 2-deep pipeline through smB[2]:
//   c 0-3: CtH (logits), c 4-7: CtP (PV), c 8-23: Wp ns=(c-8)>>2 kc=(c-8)&3.
// smA: stage M rows -> P (post-softmax) -> Yt. Waves split N: 32 cols each.
__global__ __launch_bounds__(512, 4) void k_fused4(
    const u16* __restrict__ Mh, const u16* __restrict__ CtH,
    const u16* __restrict__ CtP, const u16* __restrict__ Wp,
    float* __restrict__ out1, float* __restrict__ out2)
{
    __shared__ __align__(16) u16 smA[16 * 256];      // 8 KB
    __shared__ __align__(16) u16 smB[2][256 * 64];   // 64 KB
    __shared__ float red[16][8];

    const int sbl = xcd_swz((int)blockIdx.x, (int)gridDim.x);
    const int b  = sbl >> 3;
    const int m0 = (sbl & 7) * 16;
    const int t = threadIdx.x;
    const int lane = t & 63, w = t >> 6;
    const int g = lane >> 4, r = lane & 15;

    const u16* Bsrc = CtH + (size_t)b * 65536;   // ctx^T [l][c]
    const u16* Psrc = CtP + (size_t)b * 65536;   // ctx   [c][l]

    auto chunk_base = [&](int c) -> const u16* {
        if (c < 4)  return Bsrc + c * 64;
        if (c < 8)  return Psrc + (c - 4) * 64;
        return Wp + (size_t)((c - 8) >> 2) * 65536 + ((c - 8) & 3) * 64;
    };

    u32x4 ub[4];
    auto BLOAD = [&](const u16* base) {
        const int row = t >> 3, grp = t & 7;
#pragma unroll
        for (int i = 0; i < 4; i++)
            ub[i] = *((const u32x4*)(base + (size_t)(i * 64 + row) * 256) + grp);
    };
    auto BSTORE = [&](int bi) {
        const int row0 = t >> 3, grp = t & 7;
#pragma unroll
        for (int i = 0; i < 4; i++) {
            const int row = i * 64 + row0;
            *(u32x4*)&smB[bi][row * 64 + ((grp ^ (row & 7)) << 3)] = ub[i];
        }
    };

    // stage A (16 rows of Mh) once: 1 pass, row = t>>5, grp = t&31
    {
        const u32x4* src = (const u32x4*)(Mh + (size_t)(b * 128 + m0) * 256);
        const int row = t >> 5, grp = t & 31;
        u32x4 v = src[row * 32 + grp];
        *(u32x4*)&smA[row * 256 + ((grp ^ (row & 7)) << 3)] = v;
    }
    // pipeline prologue: chunk0 -> buf0, chunk1 -> regs
    BLOAD(chunk_base(0));
    BSTORE(0);
    BLOAD(chunk_base(1));
    __syncthreads();

    // ---- logits: chunks 0-3; acc[ni][rr] = logit[4g+rr][w*32+16ni+r]
    f32x4 acc[2] = {};
#pragma unroll
    for (int kc = 0; kc < 4; kc++) {
#pragma unroll
        for (int kh = 0; kh < 2; kh++) {
            const int kq = kc * 2 + kh;
            f16x8 aF = *(const f16x8*)&smA[r * 256 + (((kq * 4 + g) ^ (r & 7)) << 3)];
#pragma unroll
            for (int ni = 0; ni < 2; ni++) {
                const int row = w * 32 + ni * 16 + r;
                f16x8 bF = *(const f16x8*)&smB[kc & 1][row * 64 + ((((kh << 2) | g) ^ (row & 7)) << 3)];
                acc[ni] = MFMA_F16(aF, bF, acc[ni]);
            }
        }
        BSTORE((kc + 1) & 1);          // store chunk kc+1
        BLOAD(chunk_base(kc + 2));     // load chunk kc+2 (2..5)
        __syncthreads();
    }

    // ---- softmax over 256 cols (8 waves share each row via red[16][8])
    float mx2[4], s4[4];
#pragma unroll
    for (int rr = 0; rr < 4; rr++) {
        float mx = fmaxf(acc[0][rr], acc[1][rr]);
#pragma unroll
        for (int m = 1; m < 16; m <<= 1) mx = fmaxf(mx, __shfl_xor(mx, m));
        mx2[rr] = mx;
    }
    if (r == 0) {
#pragma unroll
        for (int rr = 0; rr < 4; rr++) red[4 * g + rr][w] = mx2[rr];
    }
    __syncthreads();
#pragma unroll
    for (int rr = 0; rr < 4; rr++) {
        const int lrow = 4 * g + rr;
        float gmx = red[lrow][0];
#pragma unroll
        for (int j = 1; j < 8; j++) gmx = fmaxf(gmx, red[lrow][j]);
        float s = 0.f;
#pragma unroll
        for (int ni = 0; ni < 2; ni++) {
            float e = __expf(acc[ni][rr] - gmx);
            acc[ni][rr] = e;
            s += e;
        }
#pragma unroll
        for (int m = 1; m < 16; m <<= 1) s += __shfl_xor(s, m);
        s4[rr] = s;
    }
    __syncthreads();
    if (r == 0) {
#pragma unroll
        for (int rr = 0; rr < 4; rr++) red[4 * g + rr][w] = s4[rr];
    }
    __syncthreads();

    // ---- normalize, park P (fp16, swizzled) into smA
#pragma unroll
    for (int rr = 0; rr < 4; rr++) {
        const int lrow = 4 * g + rr;
        float inv = red[lrow][0];
#pragma unroll
        for (int j = 1; j < 8; j++) inv += red[lrow][j];
        inv = 1.f / inv;
#pragma unroll
        for (int ni = 0; ni < 2; ni++) {
            const float v = acc[ni][rr] * inv;
            const int col = w * 32 + ni * 16 + r;
            smA[lrow * 256 + (((col >> 3) ^ (lrow & 7)) << 3) + (col & 7)] = f2h(v);
        }
    }
    __syncthreads();

    // ---- out2 = P^T, coalesced: threads 0-255, column l = t, 64 B run
    if (t < 256) {
        const int l = t;
        float vals[16];
#pragma unroll
        for (int row = 0; row < 16; row++)
            vals[row] = h2f(smA[row * 256 + (((l >> 3) ^ (row & 7)) << 3) + (l & 7)]);
        float4* dst = (float4*)(out2 + (size_t)b * 32768 + (size_t)l * 128 + m0);
#pragma unroll
        for (int q = 0; q < 4; q++)
            dst[q] = make_float4(vals[4 * q], vals[4 * q + 1],
                                 vals[4 * q + 2], vals[4 * q + 3]);
    }

    // ---- PV: chunks 4-7; Yt[i][c] = sum_l P[i][l] * ctx[c][l]
    f32x4 acc2[2] = {};
#pragma unroll
    for (int kc = 0; kc < 4; kc++) {
#pragma unroll
        for (int kh = 0; kh < 2; kh++) {
            const int kq = kc * 2 + kh;
            f16x8 aF = *(const f16x8*)&smA[r * 256 + (((kq * 4 + g) ^ (r & 7)) << 3)];
#pragma unroll
            for (int ni = 0; ni < 2; ni++) {
                const int row = w * 32 + ni * 16 + r;
                f16x8 bF = *(const f16x8*)&smB[kc & 1][row * 64 + ((((kh << 2) | g) ^ (row & 7)) << 3)];
                acc2[ni] = MFMA_F16(aF, bF, acc2[ni]);
            }
        }
        BSTORE((kc + 1) & 1);          // store chunk kc+5
        BLOAD(chunk_base(kc + 6));     // load chunk kc+6 (6..9)
        __syncthreads();
    }

    // ---- park Yt (fp16, swizzled) into smA (P dead after PV)
#pragma unroll
    for (int rr = 0; rr < 4; rr++) {
        const int lrow = 4 * g + rr;
#pragma unroll
        for (int ni = 0; ni < 2; ni++) {
            const int col = w * 32 + ni * 16 + r;
            smA[lrow * 256 + (((col >> 3) ^ (lrow & 7)) << 3) + (col & 7)] = f2h(acc2[ni][rr]);
        }
    }
    __syncthreads();

    // ---- out1 = Yt @ W^T': chunks 8-23 (ns = j>>2, kc = j&3)
    f16x8 aY[8];
#pragma unroll
    for (int kq = 0; kq < 8; kq++)
        aY[kq] = *(const f16x8*)&smA[r * 256 + (((kq * 4 + g) ^ (r & 7)) << 3)];

    const size_t gi0 = (size_t)(b * 128 + m0);
    f32x4 acc3[2];
#pragma unroll
    for (int j = 0; j < 16; j++) {
        if ((j & 3) == 0) { acc3[0] = (f32x4){}; acc3[1] = (f32x4){}; }
#pragma unroll
        for (int kh = 0; kh < 2; kh++) {
            f16x8 aF = aY[(j & 3) * 2 + kh];
#pragma unroll
            for (int ni = 0; ni < 2; ni++) {
                const int row = w * 32 + ni * 16 + r;
                f16x8 bF = *(const f16x8*)&smB[j & 1][row * 64 + ((((kh << 2) | g) ^ (row & 7)) << 3)];
                acc3[ni] = MFMA_F16(aF, bF, acc3[ni]);
            }
        }
        if ((j & 3) == 3) {            // write super-chunk ns
            const int ns = j >> 2;
#pragma unroll
            for (int ni = 0; ni < 2; ni++) {
                const int col = ns * 256 + w * 32 + ni * 16 + r;
#pragma unroll
                for (int rr = 0; rr < 4; rr++)
                    out1[(gi0 + 4 * g + rr) * 1024 + col] = acc3[ni][rr];
            }
        }
        if (j < 15) BSTORE((j + 1) & 1);               // store chunk 9+j
        if (j < 14) BLOAD(chunk_base(10 + j));         // load chunk 10+j
        if (j < 15) __syncthreads();
    }
}

// ---------------------------------------------------------------------------
extern "C" void kernel_launch(void* const* d_in, const int* in_sizes, int n_in,
                              void* d_out, int out_size, void* d_ws, size_t ws_size,
                              hipStream_t stream) {
    const int B = 64, IDF = 128, CDF = 256, L = 256, S2 = 1024;
    const float* wc  = (const float*)d_in[0];   // [B, IDF, S2] = [8192][1024]
    const float* ctx = (const float*)d_in[1];   // [B, CDF, L]
    const float* W   = (const float*)d_in[2];   // [S2, CDF]
    float* out1 = (float*)d_out;                          // [B,IDF,S2]
    float* out2 = (float*)d_out + (size_t)B * IDF * S2;   // [B,L,IDF]

    char* ws = (char*)d_ws;
    size_t off = 0;
    auto alloc = [&](size_t bytes) -> char* {
        char* p = ws + off;
        off += (bytes + 255) & ~(size_t)255;
        return p;
    };
    u16* WtH = (u16*)alloc((size_t)CDF * S2 * 2);        // W^T fp16 [256][1024]
    u16* Wp  = (u16*)alloc((size_t)S2 * CDF * 2);        // W   fp16 [1024][256]
    u16* CtH = (u16*)alloc((size_t)B * L * CDF * 2);     // ctx^T fp16 [B][l][c]
    u16* CtP = (u16*)alloc((size_t)B * CDF * L * 2);     // ctx fp16  [B][c][l]
    u16* MH  = (u16*)alloc((size_t)B * IDF * CDF * 2);   // M fp16 [8192][256]
    (void)ws_size; // ~22 MB

    // converts: ctx -> CtH + CtP ; W -> WtH + Wp
    k_tcvt_all<<<dim3(8, 8, 68), 256, 0, stream>>>(W, ctx, WtH, Wp, CtH, CtP);

    // G1: M = wc @ W (A = wc f32 on-fly, BT = WtH), 64x64, 512 thr, 512 blocks
    k_gemm9<<<512, 512, 0, stream>>>(wc, WtH, MH);

    // FUSED: logits + softmax + out2 + PV + out1, 512 thr, 512 blocks
    k_fused4<<<512, 512, 0, stream>>>(MH, CtH, CtP, Wp, out1, out2);
}